// Round 3
// baseline (236.283 us; speedup 1.0000x reference)
//
#include <hip/hip_runtime.h>

// Weighted BP decoder, (3,6)-regular Tanner graph.
// Check r owns edges 6r..6r+5 (row-major nonzeros of H) -> check-side extrinsic
// products are in-register prefix/suffix products (c_prod_idx unused).
//
// Messages in log2 domain: d = c2v/ln2. With z = exp2(a), t = tanh(a*ln2/2)
// = (z-1)/(z+1); extrinsic product p = A/B with A = prod(z-1), B = prod(z+1)
// (all-but-one). Then
//   d_new = log2(B + kappa*A) - log2(B - kappa*A)
// -> per edge-row transcendentals: exp2 + 2*log2 (tanh/atanh never formed).
// Exponent clamped at 24 (== z <= 2^24): 5-way products <= 2^120, and
// B >= |A| keeps both log args >= (1-kappa)*B > 0.
//
// R8: back to ROWS=4 (R7 proved ROWS=2 costs +24us of per-block overhead at
// unchanged occupancy; R4/R5/R7 triangulate the LDS co-residency pool at
// ~96KB so 4 blocks/CU is unreachable anyway). Attack the barrier structure
// instead:
//  - DOUBLE-BUFFERED messages: iter t reads buf[t&1], writes buf[1-(t&1)].
//    The read-before-overwrite barrier disappears -> ONE barrier/iter, and
//    gathers/compute/writes form one region the scheduler can interleave.
//    LDS 2*3072*16 = 98304 B -> deliberately 1 block/CU (8 waves): the
//    barrier that the 2nd block was covering is half-gone, per-thread ILP=4
//    rows keeps issue busy, and next-iter uniform loads hide under the
//    ~1.5K-cycle compute region.
//  - LDS slot indices precomputed & unpacked in VGPRs (R5's 2x16b packing
//    cost ~36 unpack VALU/iter). Buffer toggle is a compile-time +EEDG via
//    the unrolled iteration pair (folds into the ds offset / one hoisted add).
//  - swizzle kept: 16B slots -> bank-quad group (s>>1)&7 steps by 3 along
//    the stride-6 slot progressions -> conflict-free b128 gathers/writes.
//  - __launch_bounds__(T,1): calibrated semantics cap = 512/(2*arg) = 256
//    VGPR (R5 (T,2)->128/used 64; R7 (T,4)->64/used 52; R6 (T,8)->32+spill).
//    Even at 256 the needed 2 waves/SIMD residency holds -> no spill path.

namespace {

typedef float v4f __attribute__((ext_vector_type(4)));

constexpr int T      = 512;   // threads/block == checks
constexpr int ROWS   = 4;     // batch rows per block (v4f-packed)
constexpr int EEDG   = 3072;
constexpr int NVAR   = 1024;
constexpr int NITER  = 10;
constexpr int BATCH  = 8192;
constexpr int NOUT   = 512;   // N - M outputs per row

constexpr float LOG2E = 1.4426950408889634f;
constexpr float LN2   = 0.6931471805599453f;
constexpr float KAPPA = 0.999995f;
constexpr float ACLMP = 24.0f;   // exp2 arg clamp == z <= 2^24

__device__ __forceinline__ float fast_exp2(float x) { return __builtin_amdgcn_exp2f(x); }
__device__ __forceinline__ float fast_log2(float x) { return __builtin_amdgcn_logf(x); }
__device__ __forceinline__ float fast_rcp (float x) { return __builtin_amdgcn_rcpf(x); }

// Bank-conflict swizzle: rotate low 5 bits of the slot right by 1.
// 16B slots: bank-quad group of swizzled slot = (s>>1)&7; stride-6 slot
// progressions across lanes -> group stride 3 (odd) -> uniform 8 lanes/group
// per b128 access = conflict-free.
__device__ __forceinline__ int swz(int s) {
    return (s & ~31) | ((s >> 1) & 15) | ((s & 1) << 4);
}

__global__ __launch_bounds__(T, 1)   // VGPR cap 256; 1 block/CU by LDS anyway
void bp_decode(const float* __restrict__ llr,
               const float* __restrict__ w_iter,
               const float* __restrict__ llr_iter,
               const float* __restrict__ w_final,
               const float* __restrict__ llr_final,
               const int*  __restrict__ v_sum_idx,
               const int*  __restrict__ edge_var,
               const int*  __restrict__ final_idx,
               float* __restrict__ out)
{
    __shared__ v4f Ad[2 * EEDG];   // 98304 B, double-buffered messages

    const int  tid = threadIdx.x;
    const long b0  = (long)blockIdx.x * ROWS;

    // ---- init: buffer A (slots 0..3071) = 0; buffer B fully written in it 0 ----
    #pragma unroll
    for (int k = 0; k < 6; ++k)
        Ad[k * T + tid] = (v4f)(0.f);   // swizzle is a bijection -> full cover

    // ---- static per-thread graph data (my check = tid, edges 6*tid..6*tid+5) ----
    int nb[12];   // 12 neighbor LDS slots (swizzled), unpacked -> zero per-iter VALU
    int own[6];   // 6 own write slots (swizzled)
    int var[6];   // 6 variable ids
    v4f Lpre[6];  // llr (4 rows) * LOG2E per edge
    {
        const int4* p = (const int4*)(v_sum_idx + 12 * tid);  // 48B-aligned
        int4 q0 = p[0], q1 = p[1], q2 = p[2];
        nb[0]  = swz(q0.x); nb[1]  = swz(q0.y); nb[2]  = swz(q0.z); nb[3]  = swz(q0.w);
        nb[4]  = swz(q1.x); nb[5]  = swz(q1.y); nb[6]  = swz(q1.z); nb[7]  = swz(q1.w);
        nb[8]  = swz(q2.x); nb[9]  = swz(q2.y); nb[10] = swz(q2.z); nb[11] = swz(q2.w);
    }
    #pragma unroll
    for (int j = 0; j < 6; ++j) own[j] = swz(6 * tid + j);
    {
        const int2* p = (const int2*)(edge_var + 6 * tid);    // 24B-aligned
        int2 q0 = p[0], q1 = p[1], q2 = p[2];
        var[0]=q0.x; var[1]=q0.y; var[2]=q1.x; var[3]=q1.y; var[4]=q2.x; var[5]=q2.y;
        #pragma unroll
        for (int j = 0; j < 6; ++j) {
            v4f L;
            L.x = llr[(b0 + 0) * NVAR + var[j]];
            L.y = llr[(b0 + 1) * NVAR + var[j]];
            L.z = llr[(b0 + 2) * NVAR + var[j]];
            L.w = llr[(b0 + 3) * NVAR + var[j]];
            Lpre[j] = L * LOG2E;
        }
    }

    // prefetch iteration 0 uniforms
    float w[12], lv[6];
    {
        const float* p = w_iter + 12 * tid;
        float4 a = ((const float4*)p)[0], b = ((const float4*)p)[1], c = ((const float4*)p)[2];
        w[0]=a.x; w[1]=a.y; w[2]=a.z;  w[3]=a.w;
        w[4]=b.x; w[5]=b.y; w[6]=b.z;  w[7]=b.w;
        w[8]=c.x; w[9]=c.y; w[10]=c.z; w[11]=c.w;
        #pragma unroll
        for (int j = 0; j < 6; ++j) lv[j] = llr_iter[var[j]];
    }

    __syncthreads();

    // One iteration: read buf at RDOFF, write buf at WROFF, ONE barrier at end.
    // Reads(t) [RD buf] and writes(t) [WR buf] are disjoint -> no intra-iter
    // barrier; the end barrier makes writes(t) visible to gathers(t+1).
#define BP_ITER(IT, RDOFF, WROFF) do {                                          \
        v4f a_[6];                                                              \
        _Pragma("unroll")                                                       \
        for (int j = 0; j < 6; ++j) a_[j] = Lpre[j] * lv[j];                    \
        _Pragma("unroll")                                                       \
        for (int i = 0; i < 6; ++i) {                                           \
            v4f ga = Ad[nb[2*i]   + (RDOFF)];   /* ds_read_b128 */              \
            v4f gb = Ad[nb[2*i+1] + (RDOFF)];                                   \
            a_[i] = a_[i] + w[2*i] * ga + w[2*i+1] * gb;                        \
        }                                                                       \
        /* prefetch next iteration's uniforms; hidden under transc phase */     \
        const int itn_ = ((IT) + 1 < NITER) ? (IT) + 1 : (IT);                  \
        const float* pw_ = w_iter + (long)itn_ * (EEDG * 2) + 12 * tid;         \
        float4 qa_ = ((const float4*)pw_)[0];                                   \
        float4 qb_ = ((const float4*)pw_)[1];                                   \
        float4 qc_ = ((const float4*)pw_)[2];                                   \
        const float* lit_ = llr_iter + itn_ * NVAR;                             \
        float lvn_[6];                                                          \
        _Pragma("unroll")                                                       \
        for (int j = 0; j < 6; ++j) lvn_[j] = lit_[var[j]];                     \
        /* z-domain check update */                                             \
        v4f zm_[6], zp_[6];                                                     \
        _Pragma("unroll")                                                       \
        for (int j = 0; j < 6; ++j) {                                           \
            v4f aa = __builtin_elementwise_min(a_[j], (v4f)(ACLMP));            \
            v4f z;                                                              \
            z.x = fast_exp2(aa.x);                                              \
            z.y = fast_exp2(aa.y);                                              \
            z.z = fast_exp2(aa.z);                                              \
            z.w = fast_exp2(aa.w);                                              \
            zm_[j] = z - 1.f;                                                   \
            zp_[j] = z + 1.f;                                                   \
        }                                                                       \
        v4f A_[6], B_[6];                                                       \
        {                                                                       \
            v4f P1=zm_[0], P2=P1*zm_[1], P3=P2*zm_[2], P4=P3*zm_[3], P5=P4*zm_[4]; \
            v4f S4=zm_[5], S3=S4*zm_[4], S2=S3*zm_[3], S1=S2*zm_[2], S0=S1*zm_[1]; \
            A_[0]=S0; A_[1]=P1*S1; A_[2]=P2*S2; A_[3]=P3*S3; A_[4]=P4*S4; A_[5]=P5; \
        }                                                                       \
        {                                                                       \
            v4f P1=zp_[0], P2=P1*zp_[1], P3=P2*zp_[2], P4=P3*zp_[3], P5=P4*zp_[4]; \
            v4f S4=zp_[5], S3=S4*zp_[4], S2=S3*zp_[3], S1=S2*zp_[2], S0=S1*zp_[1]; \
            B_[0]=S0; B_[1]=P1*S1; B_[2]=P2*S2; B_[3]=P3*S3; B_[4]=P4*S4; B_[5]=P5; \
        }                                                                       \
        _Pragma("unroll")                                                       \
        for (int j = 0; j < 6; ++j) {                                           \
            v4f num = KAPPA * A_[j] + B_[j];    /* pk fma */                    \
            v4f den = B_[j] - KAPPA * A_[j];    /* pk fma */                    \
            v4f d;                                                              \
            d.x = fast_log2(num.x) - fast_log2(den.x);                          \
            d.y = fast_log2(num.y) - fast_log2(den.y);                          \
            d.z = fast_log2(num.z) - fast_log2(den.z);                          \
            d.w = fast_log2(num.w) - fast_log2(den.w);                          \
            Ad[own[j] + (WROFF)] = d;           /* ds_write_b128 */             \
        }                                                                       \
        /* rotate prefetched uniforms into place */                             \
        w[0]=qa_.x; w[1]=qa_.y; w[2]=qa_.z;  w[3]=qa_.w;                        \
        w[4]=qb_.x; w[5]=qb_.y; w[6]=qb_.z;  w[7]=qb_.w;                        \
        w[8]=qc_.x; w[9]=qc_.y; w[10]=qc_.z; w[11]=qc_.w;                       \
        _Pragma("unroll")                                                       \
        for (int j = 0; j < 6; ++j) lv[j] = lvn_[j];                            \
        __syncthreads();                                                        \
    } while (0)

    for (int it = 0; it < NITER; it += 2) {
        BP_ITER(it,     0,    EEDG);   // read A, write B
        BP_ITER(it + 1, EEDG, 0);      // read B, write A
    }
#undef BP_ITER
    // NITER even -> final messages (iter 9's writes) land in buffer A (offset 0)

    // ---- final marginalization: variable tid (the 512 output vars), 4 rows ----
    {
        int f0 = swz(final_idx[3*tid]), f1 = swz(final_idx[3*tid + 1]), f2 = swz(final_idx[3*tid + 2]);
        v4f d0 = Ad[f0];
        v4f d1 = Ad[f1];
        v4f d2 = Ad[f2];
        float wf0 = w_final[3*tid], wf1 = w_final[3*tid + 1], wf2 = w_final[3*tid + 2];
        float lf  = llr_final[tid];
        v4f l;
        l.x = llr[(b0 + 0) * NVAR + tid];
        l.y = llr[(b0 + 1) * NVAR + tid];
        l.z = llr[(b0 + 2) * NVAR + tid];
        l.w = llr[(b0 + 3) * NVAR + tid];

        v4f fin = (d0 * wf0 + d1 * wf1 + d2 * wf2) * LN2;   // c2v = ln2 * d
        v4f v   = l * lf + fin;
        out[(b0 + 0) * NOUT + tid] = fast_rcp(1.f + fast_exp2(-v.x * LOG2E));
        out[(b0 + 1) * NOUT + tid] = fast_rcp(1.f + fast_exp2(-v.y * LOG2E));
        out[(b0 + 2) * NOUT + tid] = fast_rcp(1.f + fast_exp2(-v.z * LOG2E));
        out[(b0 + 3) * NOUT + tid] = fast_rcp(1.f + fast_exp2(-v.w * LOG2E));
    }
}

} // namespace

extern "C" void kernel_launch(void* const* d_in, const int* in_sizes, int n_in,
                              void* d_out, int out_size, void* d_ws, size_t ws_size,
                              hipStream_t stream)
{
    const float* llr       = (const float*)d_in[0];
    const float* w_iter    = (const float*)d_in[1];
    const float* llr_iter  = (const float*)d_in[2];
    const float* w_final   = (const float*)d_in[3];
    const float* llr_final = (const float*)d_in[4];
    const int*   v_sum_idx = (const int*)d_in[5];
    // d_in[6] = c_prod_idx: unused (check groups are consecutive by construction)
    const int*   edge_var  = (const int*)d_in[7];
    const int*   final_idx = (const int*)d_in[8];
    float* outp = (float*)d_out;

    dim3 grid(BATCH / ROWS), block(T);
    hipLaunchKernelGGL(bp_decode, grid, block, 0, stream,
                       llr, w_iter, llr_iter, w_final, llr_final,
                       v_sum_idx, edge_var, final_idx, outp);
}

// Round 4
// 206.604 us; speedup vs baseline: 1.1437x; 1.1437x over previous
//
#include <hip/hip_runtime.h>

// Weighted BP decoder, (3,6)-regular Tanner graph.
// Check r owns edges 6r..6r+5 (row-major nonzeros of H) -> check-side extrinsic
// products are in-register prefix/suffix products (c_prod_idx unused).
//
// Messages in log2 domain: d = c2v/ln2. With z = exp2(a), t = tanh(a*ln2/2)
// = (z-1)/(z+1); extrinsic product p = A/B with A = prod(z-1), B = prod(z+1)
// (all-but-one). Then
//   d_new = log2(B + kappa*A) - log2(B - kappa*A)
// -> per edge-row transcendentals: exp2 + 2*log2 (tanh/atanh never formed).
// Exponent clamped at 24 (== z <= 2^24): 5-way products <= 2^120, and
// B >= |A| keeps both log args >= (1-kappa)*B > 0.
//
// R9 = R5 (the verified optimum of the occupancy landscape) + the two things
// R6-R8 validated in isolation.
//
// Occupancy model (consistent with ALL session measurements):
//   VGPR file = 256/lane/SIMD; __launch_bounds__(T,n) = min-waves-per-EU ->
//   VGPR cap = 256/n; waves/SIMD = floor(256/VGPR_Count), cap 8.
//   Throughput currency = rows-in-flight/SIMD = waves/SIMD * ROWS; both
//   factors trade against the same VGPR file. ROWS=4 @ 64 VGPR -> 16
//   rows/SIMD is the optimum (ROWS=2@52 -> 8; VGPR>64 halves waves;
//   6 waves/SIMD needs VGPR<=42, unreachable at ROWS>=2).
//   R8 (1 block, 8 waves, 1 barrier/iter) lost to R5 (2 blocks, 16 waves,
//   2 barriers/iter): TLP cover beats barrier elimination here.
//
// Changes vs R5:
//  - LDS slot swizzle (validated in R8: conflicts 1.62e7 -> 9.2e5 at this
//    exact geometry): swz(s) = rot-right-1 of low 5 slot bits. 16B slots:
//    bank-quad group = (s>>1)&7; stride-6 slot progressions across lanes ->
//    group stride 3 (odd) -> conflict-free b128 gathers AND own-slot writes.
//    Gather slots swizzled once at init (packed 16b, VGPR-neutral); write
//    slots recomputed inline (3 VALU each, lets allocator rematerialize
//    instead of holding 6 regs).
//  - __launch_bounds__(T,4): pins VGPR cap at exactly 64 (R5 hit 64 under a
//    128 cap by luck). 4 waves/SIMD * ROWS=4 = 16 rows in flight.

namespace {

typedef float v4f __attribute__((ext_vector_type(4)));

constexpr int T      = 512;   // threads/block == checks
constexpr int ROWS   = 4;     // batch rows per block (v4f-packed)
constexpr int EEDG   = 3072;
constexpr int NVAR   = 1024;
constexpr int NITER  = 10;
constexpr int BATCH  = 8192;
constexpr int NOUT   = 512;   // N - M outputs per row

constexpr float LOG2E = 1.4426950408889634f;
constexpr float LN2   = 0.6931471805599453f;
constexpr float KAPPA = 0.999995f;
constexpr float ACLMP = 24.0f;   // exp2 arg clamp == z <= 2^24

__device__ __forceinline__ float fast_exp2(float x) { return __builtin_amdgcn_exp2f(x); }
__device__ __forceinline__ float fast_log2(float x) { return __builtin_amdgcn_logf(x); }
__device__ __forceinline__ float fast_rcp (float x) { return __builtin_amdgcn_rcpf(x); }

// Bank-conflict swizzle: rotate low 5 bits of the slot right by 1 (bijective
// within every 32-slot chunk; 3072 = 96*32, swizzled slots stay in [0,3072)).
__device__ __forceinline__ int swz(int s) {
    return (s & ~31) | ((s >> 1) & 15) | ((s & 1) << 4);
}

__global__ __launch_bounds__(T, 4)   // min 4 waves/EU -> VGPR cap 256/4 = 64
void bp_decode(const float* __restrict__ llr,
               const float* __restrict__ w_iter,
               const float* __restrict__ llr_iter,
               const float* __restrict__ w_final,
               const float* __restrict__ llr_final,
               const int*  __restrict__ v_sum_idx,
               const int*  __restrict__ edge_var,
               const int*  __restrict__ final_idx,
               float* __restrict__ out)
{
    __shared__ v4f Ad[EEDG];   // 49152 B; 2 blocks/CU co-resident

    const int  tid = threadIdx.x;
    const long b0  = (long)blockIdx.x * ROWS;

    // ---- init: d = 0 (swizzle is a bijection -> full cover) ----
    #pragma unroll
    for (int k = 0; k < 6; ++k)
        Ad[k * T + tid] = (v4f)(0.f);

    // ---- static per-thread graph data (my check = tid, edges 6*tid..6*tid+5) ----
    unsigned nbp[6];    // my 12 neighbor LDS slots (swizzled), 2x16b packed
    unsigned varp[3];   // my 6 variable ids, 2x16b packed
    v4f      Lpre[6];   // llr (4 rows) * LOG2E per edge
    {
        const int4* p = (const int4*)(v_sum_idx + 12 * tid);  // 48B-aligned
        int4 q0 = p[0], q1 = p[1], q2 = p[2];
        nbp[0] = (unsigned)swz(q0.x) | ((unsigned)swz(q0.y) << 16);
        nbp[1] = (unsigned)swz(q0.z) | ((unsigned)swz(q0.w) << 16);
        nbp[2] = (unsigned)swz(q1.x) | ((unsigned)swz(q1.y) << 16);
        nbp[3] = (unsigned)swz(q1.z) | ((unsigned)swz(q1.w) << 16);
        nbp[4] = (unsigned)swz(q2.x) | ((unsigned)swz(q2.y) << 16);
        nbp[5] = (unsigned)swz(q2.z) | ((unsigned)swz(q2.w) << 16);
    }
    {
        int var[6];
        const int2* p = (const int2*)(edge_var + 6 * tid);    // 24B-aligned
        int2 q0 = p[0], q1 = p[1], q2 = p[2];
        var[0]=q0.x; var[1]=q0.y; var[2]=q1.x; var[3]=q1.y; var[4]=q2.x; var[5]=q2.y;
        #pragma unroll
        for (int i = 0; i < 3; ++i)
            varp[i] = (unsigned)var[2*i] | ((unsigned)var[2*i+1] << 16);
        #pragma unroll
        for (int j = 0; j < 6; ++j) {
            v4f L;
            L.x = llr[(b0 + 0) * NVAR + var[j]];
            L.y = llr[(b0 + 1) * NVAR + var[j]];
            L.z = llr[(b0 + 2) * NVAR + var[j]];
            L.w = llr[(b0 + 3) * NVAR + var[j]];
            Lpre[j] = L * LOG2E;
        }
    }

    const int own = 6 * tid;

    // prefetch iteration 0 uniforms
    float w[12], lv[6];
    {
        const float* p = w_iter + 12 * tid;
        float4 a = ((const float4*)p)[0], b = ((const float4*)p)[1], c = ((const float4*)p)[2];
        w[0]=a.x; w[1]=a.y; w[2]=a.z;  w[3]=a.w;
        w[4]=b.x; w[5]=b.y; w[6]=b.z;  w[7]=b.w;
        w[8]=c.x; w[9]=c.y; w[10]=c.z; w[11]=c.w;
        #pragma unroll
        for (int i = 0; i < 3; ++i) {
            unsigned q = varp[i];
            lv[2*i]   = llr_iter[q & 0xffffu];
            lv[2*i+1] = llr_iter[q >> 16];
        }
    }

    __syncthreads();

    #pragma unroll 2
    for (int it = 0; it < NITER; ++it) {
        // accumulators seeded with channel term; LDS gathers folded in
        // immediately (peak live small -> no spills)
        v4f a[6];
        #pragma unroll
        for (int j = 0; j < 6; ++j) a[j] = Lpre[j] * lv[j];
        #pragma unroll
        for (int i = 0; i < 6; ++i) {
            unsigned p  = nbp[i];
            v4f ga = Ad[p & 0xffffu];     // ds_read_b128, conflict-free
            v4f gb = Ad[p >> 16];
            a[i] = a[i] + w[2*i] * ga + w[2*i+1] * gb;   // pk fma
        }

        __syncthreads();   // all gathers landed before anyone overwrites in place

        // prefetch next iteration's uniforms; latency hides under transc phase
        {
            const int itn = (it + 1 < NITER) ? it + 1 : it;   // clamp, no OOB
            const float* p = w_iter + itn * (EEDG * 2) + 12 * tid;
            float4 qa = ((const float4*)p)[0], qb = ((const float4*)p)[1], qc = ((const float4*)p)[2];
            const float* lit = llr_iter + itn * NVAR;
            float lvn[6];
            #pragma unroll
            for (int i = 0; i < 3; ++i) {
                unsigned q = varp[i];
                lvn[2*i]   = lit[q & 0xffffu];
                lvn[2*i+1] = lit[q >> 16];
            }

            // z-domain check update (uses current w, lv via a[])
            v4f zm[6], zp[6];
            #pragma unroll
            for (int j = 0; j < 6; ++j) {
                v4f aa = __builtin_elementwise_min(a[j], (v4f)(ACLMP));
                v4f z;
                z.x = fast_exp2(aa.x);
                z.y = fast_exp2(aa.y);
                z.z = fast_exp2(aa.z);
                z.w = fast_exp2(aa.w);
                zm[j] = z - 1.f;
                zp[j] = z + 1.f;
            }
            v4f A[6], B[6];
            {
                v4f P1=zm[0], P2=P1*zm[1], P3=P2*zm[2], P4=P3*zm[3], P5=P4*zm[4];
                v4f S4=zm[5], S3=S4*zm[4], S2=S3*zm[3], S1=S2*zm[2], S0=S1*zm[1];
                A[0]=S0; A[1]=P1*S1; A[2]=P2*S2; A[3]=P3*S3; A[4]=P4*S4; A[5]=P5;
            }
            {
                v4f P1=zp[0], P2=P1*zp[1], P3=P2*zp[2], P4=P3*zp[3], P5=P4*zp[4];
                v4f S4=zp[5], S3=S4*zp[4], S2=S3*zp[3], S1=S2*zp[2], S0=S1*zp[1];
                B[0]=S0; B[1]=P1*S1; B[2]=P2*S2; B[3]=P3*S3; B[4]=P4*S4; B[5]=P5;
            }
            #pragma unroll
            for (int j = 0; j < 6; ++j) {
                v4f num = KAPPA * A[j] + B[j];    // pk fma
                v4f den = B[j] - KAPPA * A[j];    // pk fma
                v4f d;
                d.x = fast_log2(num.x) - fast_log2(den.x);
                d.y = fast_log2(num.y) - fast_log2(den.y);
                d.z = fast_log2(num.z) - fast_log2(den.z);
                d.w = fast_log2(num.w) - fast_log2(den.w);
                Ad[swz(own + j)] = d;             // ds_write_b128, conflict-free
            }

            // rotate prefetched uniforms into place (unroll-2 elides the movs)
            w[0]=qa.x; w[1]=qa.y; w[2]=qa.z;  w[3]=qa.w;
            w[4]=qb.x; w[5]=qb.y; w[6]=qb.z;  w[7]=qb.w;
            w[8]=qc.x; w[9]=qc.y; w[10]=qc.z; w[11]=qc.w;
            #pragma unroll
            for (int j = 0; j < 6; ++j) lv[j] = lvn[j];
        }

        __syncthreads();   // writes visible before next iteration's gathers
    }

    // ---- final marginalization: variable tid (the 512 output vars), 4 rows ----
    {
        int f0 = swz(final_idx[3*tid]), f1 = swz(final_idx[3*tid + 1]), f2 = swz(final_idx[3*tid + 2]);
        v4f d0 = Ad[f0];
        v4f d1 = Ad[f1];
        v4f d2 = Ad[f2];
        float wf0 = w_final[3*tid], wf1 = w_final[3*tid + 1], wf2 = w_final[3*tid + 2];
        float lf  = llr_final[tid];
        v4f l;
        l.x = llr[(b0 + 0) * NVAR + tid];
        l.y = llr[(b0 + 1) * NVAR + tid];
        l.z = llr[(b0 + 2) * NVAR + tid];
        l.w = llr[(b0 + 3) * NVAR + tid];

        v4f fin = (d0 * wf0 + d1 * wf1 + d2 * wf2) * LN2;   // c2v = ln2 * d
        v4f v   = l * lf + fin;
        out[(b0 + 0) * NOUT + tid] = fast_rcp(1.f + fast_exp2(-v.x * LOG2E));
        out[(b0 + 1) * NOUT + tid] = fast_rcp(1.f + fast_exp2(-v.y * LOG2E));
        out[(b0 + 2) * NOUT + tid] = fast_rcp(1.f + fast_exp2(-v.z * LOG2E));
        out[(b0 + 3) * NOUT + tid] = fast_rcp(1.f + fast_exp2(-v.w * LOG2E));
    }
}

} // namespace

extern "C" void kernel_launch(void* const* d_in, const int* in_sizes, int n_in,
                              void* d_out, int out_size, void* d_ws, size_t ws_size,
                              hipStream_t stream)
{
    const float* llr       = (const float*)d_in[0];
    const float* w_iter    = (const float*)d_in[1];
    const float* llr_iter  = (const float*)d_in[2];
    const float* w_final   = (const float*)d_in[3];
    const float* llr_final = (const float*)d_in[4];
    const int*   v_sum_idx = (const int*)d_in[5];
    // d_in[6] = c_prod_idx: unused (check groups are consecutive by construction)
    const int*   edge_var  = (const int*)d_in[7];
    const int*   final_idx = (const int*)d_in[8];
    float* outp = (float*)d_out;

    dim3 grid(BATCH / ROWS), block(T);
    hipLaunchKernelGGL(bp_decode, grid, block, 0, stream,
                       llr, w_iter, llr_iter, w_final, llr_final,
                       v_sum_idx, edge_var, final_idx, outp);
}